// Round 13
// baseline (220.158 us; speedup 1.0000x reference)
//
#include <hip/hip_runtime.h>
#include <cmath>

typedef _Float16 half8 __attribute__((ext_vector_type(8)));
typedef float f32x4 __attribute__((ext_vector_type(4)));

constexpr int D   = 512;
constexpr int NC  = 225;   // classes
constexpr int NPC = 224;   // outputs per class
constexpr int N1  = 256;   // padded W1 cols
constexpr int TB  = 32;    // tokens per chunk

// ws layout (int units)
constexpr int WS_NCHUNK = 0;
constexpr int WS_CHUNK  = 16;        // 962*4 ints (cls,start,cnt,colhalf)
constexpr int WS_ORDER  = 4096;      // 4096 ids grouped by class
constexpr int WS_B1P    = 8192;      // 256 floats padded b1
constexpr int WS_W1H    = 8448;      // 256*512 halves, [col][k]
constexpr int WS_W1L    = 73984;
constexpr int WS_XH     = 139520;    // 4096*512 halves
constexpr int WS_XL     = 1188096;
constexpr int WS_STAT   = 2236672;   // 4096 * 16 * float4 {m,s,e,0}; ph1 g0-7, ph2 g8-15

// fp16 split: hi = RTN(v), flushed to 0 if subnormal; lo = RTN((v-hi)*2048)
__device__ __forceinline__ void f16split(float v, _Float16& h, _Float16& l) {
    _Float16 hh = (_Float16)v;
    float hf = (float)hh;
    if (fabsf(hf) < 6.104e-5f) { hh = (_Float16)0.f; hf = 0.f; }
    h = hh;
    l = (_Float16)((v - hf) * 2048.0f);
}

// ---------- merged prep (block 0) + convert pre-pass (blocks 1..) ----------
__global__ __launch_bounds__(256) void k_prep_pre(
    const float* __restrict__ x, const float* __restrict__ W1,
    const float* __restrict__ b1, const int* __restrict__ target,
    int* __restrict__ ws, int ntok)
{
    const int bid = blockIdx.x, tid = threadIdx.x;
    if (bid == 0) {
        __shared__ int h[256], sc[256], sc2[256], cur[NC];
        h[tid] = 0;
        __syncthreads();
        for (int n = tid; n < ntok; n += 256) atomicAdd(&h[target[n] / NPC], 1);
        __syncthreads();
        const int hv = h[tid];
        sc[tid] = hv; __syncthreads();
        for (int o = 1; o < 256; o <<= 1) {
            int a = (tid >= o) ? sc[tid - o] : 0;
            __syncthreads();
            sc[tid] += a;
            __syncthreads();
        }
        const int start = sc[tid] - hv;
        const int nch = (tid < NC) ? (hv + TB - 1) / TB : 0;
        sc2[tid] = nch; __syncthreads();
        for (int o = 1; o < 256; o <<= 1) {
            int a = (tid >= o) ? sc2[tid - o] : 0;
            __syncthreads();
            sc2[tid] += a;
            __syncthreads();
        }
        const int nch2 = sc2[255];
        if (tid < NC) {
            cur[tid] = start;
            const int cb = sc2[tid] - nch;
            for (int j = 0; j < nch; ++j) {
                for (int q = 0; q < 2; ++q) {
                    const int e = WS_CHUNK + (((cb + j) * 2) + q) * 4;
                    ws[e + 0] = tid;
                    ws[e + 1] = start + j * TB;
                    ws[e + 2] = min(TB, hv - j * TB);
                    ws[e + 3] = q;
                }
            }
        }
        const int P1C = ntok / TB;      // 128
        if (tid < P1C) {
            for (int q = 0; q < 2; ++q) {
                const int e = WS_CHUNK + (nch2 * 2 + tid * 2 + q) * 4;
                ws[e + 0] = -1;
                ws[e + 1] = tid * TB;
                ws[e + 2] = TB;
                ws[e + 3] = q;
            }
        }
        if (tid == 0) ws[WS_NCHUNK] = nch2 * 2 + P1C * 2;
        __syncthreads();
        for (int n = tid; n < ntok; n += 256) {
            const int c = target[n] / NPC;
            const int pos = atomicAdd(&cur[c], 1);
            ws[WS_ORDER + pos] = n;
        }
        return;
    }
    const int pb = bid - 1;
    _Float16* xh  = (_Float16*)(ws + WS_XH);
    _Float16* xl  = (_Float16*)(ws + WS_XL);
    _Float16* w1h = (_Float16*)(ws + WS_W1H);
    _Float16* w1l = (_Float16*)(ws + WS_W1L);
    const int XBLK = (ntok * D) / (256 * 8);           // 1024
    if (pb < XBLK) {
        const int base = (pb * 256 + tid) * 8;
        const float4 a = *(const float4*)(x + base);
        const float4 b = *(const float4*)(x + base + 4);
        const float v[8] = {a.x, a.y, a.z, a.w, b.x, b.y, b.z, b.w};
        half8 hv, lv;
        #pragma unroll
        for (int j = 0; j < 8; ++j) {
            _Float16 hq, lq;
            f16split(v[j], hq, lq);
            hv[j] = hq; lv[j] = lq;
        }
        *(half8*)(xh + base) = hv;
        *(half8*)(xl + base) = lv;
    } else if (pb < XBLK + 64) {
        const int oi = ((pb - XBLK) * 256 + tid) * 8;  // [c][k], 8 k each
        const int c = oi >> 9, k0 = oi & 511;
        half8 hv, lv;
        #pragma unroll
        for (int j = 0; j < 8; ++j) {
            const float v = (c < NC) ? W1[(size_t)(k0 + j) * NC + c] : 0.f;
            _Float16 hq, lq;
            f16split(v, hq, lq);
            hv[j] = hq; lv[j] = lq;
        }
        *(half8*)(w1h + oi) = hv;
        *(half8*)(w1l + oi) = lv;
    } else {
        float* b1p = (float*)ws + WS_B1P;
        if (tid < N1) b1p[tid] = (tid < NC) ? b1[tid] : 0.f;
    }
}

// load 2x8 W scalars (phase 2)
#define LW(buf, kk)                                                              \
    do {                                                                         \
        _Pragma("unroll")                                                        \
        for (int mi = 0; mi < 2; ++mi) if (tval[mi]) {                           \
            const float* p_ = wpm[mi] + (size_t)((kk) + l4 * 8) * NPC;           \
            _Pragma("unroll")                                                    \
            for (int j = 0; j < 8; ++j) buf[mi][j] = p_[(size_t)j * NPC];        \
        }                                                                        \
    } while (0)

// load B fragments from pre-converted x
#define LX(bh, bl, kk)                                                           \
    do {                                                                         \
        _Pragma("unroll")                                                        \
        for (int n = 0; n < 2; ++n) if (n < ntiles) {                            \
            bh[n] = *(const half8*)(xh + xoff[n] + (kk) + l4 * 8);               \
            bl[n] = *(const half8*)(xl + xoff[n] + (kk) + l4 * 8);               \
        }                                                                        \
    } while (0)

// load A fragments from pre-converted W1
#define LA(ah, al, kk)                                                           \
    do {                                                                         \
        _Pragma("unroll")                                                        \
        for (int mi = 0; mi < 2; ++mi) if (tval[mi]) {                           \
            const int col_ = (mt0 + mi) * 16 + l15;                              \
            ah[mi] = *(const half8*)(w1h + (size_t)col_ * D + (kk) + l4 * 8);    \
            al[mi] = *(const half8*)(w1l + (size_t)col_ * D + (kk) + l4 * 8);    \
        }                                                                        \
    } while (0)

// split W regs + 12 MFMA (phase 2)
#define PROCW(buf, bh, bl)                                                       \
    do {                                                                         \
        _Pragma("unroll")                                                        \
        for (int mi = 0; mi < 2; ++mi) if (tval[mi]) {                           \
            half8 Ah_, Al_;                                                      \
            _Pragma("unroll")                                                    \
            for (int j = 0; j < 8; ++j) {                                        \
                _Float16 hq_, lq_;                                               \
                f16split(buf[mi][j], hq_, lq_);                                  \
                Ah_[j] = hq_; Al_[j] = lq_;                                      \
            }                                                                    \
            _Pragma("unroll")                                                    \
            for (int n = 0; n < 2; ++n) if (n < ntiles) {                        \
                accA[mi][n] = __builtin_amdgcn_mfma_f32_16x16x32_f16(Ah_, bh[n], accA[mi][n], 0, 0, 0); \
                accB[mi][n] = __builtin_amdgcn_mfma_f32_16x16x32_f16(Ah_, bl[n], accB[mi][n], 0, 0, 0); \
                accB[mi][n] = __builtin_amdgcn_mfma_f32_16x16x32_f16(Al_, bh[n], accB[mi][n], 0, 0, 0); \
            }                                                                    \
        }                                                                        \
    } while (0)

// 12 MFMA from preloaded A (phase 1)
#define PROCA(ah, al, bh, bl)                                                    \
    do {                                                                         \
        _Pragma("unroll")                                                        \
        for (int mi = 0; mi < 2; ++mi) if (tval[mi]) {                           \
            _Pragma("unroll")                                                    \
            for (int n = 0; n < 2; ++n) if (n < ntiles) {                        \
                accA[mi][n] = __builtin_amdgcn_mfma_f32_16x16x32_f16(ah[mi], bh[n], accA[mi][n], 0, 0, 0); \
                accB[mi][n] = __builtin_amdgcn_mfma_f32_16x16x32_f16(ah[mi], bl[n], accB[mi][n], 0, 0, 0); \
                accB[mi][n] = __builtin_amdgcn_mfma_f32_16x16x32_f16(al[mi], bh[n], accB[mi][n], 0, 0, 0); \
            }                                                                    \
        }                                                                        \
    } while (0)

// ---------- main: 8-wave blocks, in-block K-split, MFMA GEMM -> stats ----------
template <bool PH2>
__device__ __forceinline__ void run_chunk(
    const int* __restrict__ target, const float* __restrict__ W2c,
    const float* __restrict__ bsrc,
    const _Float16* __restrict__ w1h, const _Float16* __restrict__ w1l,
    const _Float16* __restrict__ xh, const _Float16* __restrict__ xl,
    int* __restrict__ ws, int* __restrict__ stok, f32x4* __restrict__ redbuf,
    int start, int cnt, int ch)
{
    constexpr int NREAL = PH2 ? NPC : NC;
    const int tid = threadIdx.x, w = tid >> 6, lane = tid & 63;
    const int wq = w & 3, kq = w >> 2;           // wave-quad, K-half
    const int l15 = lane & 15, l4 = lane >> 4;
    const int kbase = kq * 256;

    if (tid < TB)
        stok[tid] = PH2 ? ws[WS_ORDER + start + min(tid, cnt - 1)] : (start + tid);
    __syncthreads();

    const int ntiles = (cnt + 15) >> 4;
    int xoff[2];
    xoff[0] = stok[l15] * D;
    xoff[1] = stok[16 + l15] * D;

    const int mt0 = ch * 8 + wq * 2;
    bool tval[2];
    tval[0] = (mt0 * 16) < NREAL;
    tval[1] = ((mt0 + 1) * 16) < NREAL;

    f32x4 accA[2][2] = {}, accB[2][2] = {};

    if constexpr (PH2) {
        const float* wpm[2];
        #pragma unroll
        for (int mi = 0; mi < 2; ++mi) {
            const int col = (mt0 + mi) * 16 + l15;
            wpm[mi] = W2c + min(col, NPC - 1);
        }
        float wra[2][8], wrb[2][8];
        half8 xha[2], xla[2], xhb[2], xlb[2];
        LW(wra, kbase); LX(xha, xla, kbase);
        for (int k0 = kbase; k0 < kbase + 256; k0 += 64) {
            LW(wrb, k0 + 32); LX(xhb, xlb, k0 + 32);
            PROCW(wra, xha, xla);
            if (k0 + 64 < kbase + 256) { LW(wra, k0 + 64); LX(xha, xla, k0 + 64); }
            PROCW(wrb, xhb, xlb);
        }
    } else {
        half8 aha[2], ala[2], ahb[2], alb[2];
        half8 xha[2], xla[2], xhb[2], xlb[2];
        LA(aha, ala, kbase); LX(xha, xla, kbase);
        for (int k0 = kbase; k0 < kbase + 256; k0 += 64) {
            LA(ahb, alb, k0 + 32); LX(xhb, xlb, k0 + 32);
            PROCA(aha, ala, xha, xla);
            if (k0 + 64 < kbase + 256) { LA(aha, ala, k0 + 64); LX(xha, xla, k0 + 64); }
            PROCA(ahb, alb, xhb, xlb);
        }
    }

    // combine accs for this K-half: red = accA + accB/2048
    f32x4 red[2][2];
    #pragma unroll
    for (int mi = 0; mi < 2; ++mi)
        #pragma unroll
        for (int n = 0; n < 2; ++n) {
            red[mi][n][0] = accA[mi][n][0] + accB[mi][n][0] * (1.f / 2048.f);
            red[mi][n][1] = accA[mi][n][1] + accB[mi][n][1] * (1.f / 2048.f);
            red[mi][n][2] = accA[mi][n][2] + accB[mi][n][2] * (1.f / 2048.f);
            red[mi][n][3] = accA[mi][n][3] + accB[mi][n][3] * (1.f / 2048.f);
        }

    // K-half reduction through LDS: waves 4-7 deposit, waves 0-3 add
    if (kq == 1) {
        #pragma unroll
        for (int mi = 0; mi < 2; ++mi)
            #pragma unroll
            for (int n = 0; n < 2; ++n)
                redbuf[(((wq * 2 + mi) * 2) + n) * 64 + lane] = red[mi][n];
    }
    __syncthreads();
    if (kq != 0) return;
    #pragma unroll
    for (int mi = 0; mi < 2; ++mi)
        #pragma unroll
        for (int n = 0; n < 2; ++n) {
            const f32x4 o = redbuf[(((wq * 2 + mi) * 2) + n) * 64 + lane];
            red[mi][n][0] += o[0]; red[mi][n][1] += o[1];
            red[mi][n][2] += o[2]; red[mi][n][3] += o[3];
        }

    // ---- epilogue: per-wave per-token partial softmax stats {m, s, e_target} ----
    float* stat = (float*)ws + WS_STAT;
    #pragma unroll
    for (int n = 0; n < 2; ++n) {
        if (n < ntiles) {
            const int tok = stok[n * 16 + l15];
            const int tt  = target[tok];
            const int tcol = PH2 ? (tt % NPC) : (tt / NPC);
            float vals[2][4];
            float mx = -1e30f;
            #pragma unroll
            for (int mi = 0; mi < 2; ++mi) {
                const int col0 = (mt0 + mi) * 16 + l4 * 4;
                const int bcol = PH2 ? min(col0, NPC - 4) : col0;
                const float4 bv = *(const float4*)(bsrc + bcol);
                #pragma unroll
                for (int r = 0; r < 4; ++r) {
                    const float v = red[mi][n][r] + (&bv.x)[r];
                    vals[mi][r] = v;
                    if (col0 + r < NREAL) mx = fmaxf(mx, v);
                }
            }
            mx = fmaxf(mx, __shfl_xor(mx, 16, 64));
            mx = fmaxf(mx, __shfl_xor(mx, 32, 64));
            float s = 0.f, e = 0.f;
            #pragma unroll
            for (int mi = 0; mi < 2; ++mi) {
                const int col0 = (mt0 + mi) * 16 + l4 * 4;
                #pragma unroll
                for (int r = 0; r < 4; ++r) {
                    const int cr = col0 + r;
                    if (cr < NREAL) {
                        const float ex = __expf(vals[mi][r] - mx);
                        s += ex;
                        if (cr == tcol) e = ex;
                    }
                }
            }
            s += __shfl_xor(s, 16, 64); s += __shfl_xor(s, 32, 64);
            e += __shfl_xor(e, 16, 64); e += __shfl_xor(e, 32, 64);
            if (l4 == 0) {
                const int g = (PH2 ? 8 : 0) + ch * 4 + wq;
                *(float4*)(stat + (size_t)tok * 64 + g * 4) = {mx, s, e, 0.f};
            }
        }
    }
}

__global__ __launch_bounds__(512, 8) void k_main(
    const int* __restrict__ target, const float* __restrict__ W2,
    const float* __restrict__ b2, int* __restrict__ ws)
{
    __shared__ int stok[TB];
    __shared__ f32x4 redbuf[16 * 64];   // 16 KB
    const int bid = blockIdx.x;
    if (bid >= ws[WS_NCHUNK]) return;
    const int4 ce = *(const int4*)(ws + WS_CHUNK + bid * 4);
    const _Float16* w1h = (const _Float16*)(ws + WS_W1H);
    const _Float16* w1l = (const _Float16*)(ws + WS_W1L);
    const _Float16* xh  = (const _Float16*)(ws + WS_XH);
    const _Float16* xl  = (const _Float16*)(ws + WS_XL);
    if (ce.x >= 0) {
        run_chunk<true>(target, W2 + (size_t)ce.x * D * NPC, b2 + ce.x * NPC,
                        w1h, w1l, xh, xl, ws, stok, redbuf, ce.y, ce.z, ce.w);
    } else {
        run_chunk<false>(target, nullptr, (const float*)ws + WS_B1P,
                         w1h, w1l, xh, xl, ws, stok, redbuf, ce.y, ce.z, ce.w);
    }
}

// ---------- combine: merge 8 stat groups per phase, out = p1*p2 ----------
__global__ __launch_bounds__(256) void k_combine(const int* __restrict__ ws,
                                                 float* __restrict__ out, int ntok) {
    const int n = blockIdx.x * 256 + threadIdx.x;
    if (n >= ntok) return;
    const float4* st = (const float4*)((const float*)ws + WS_STAT) + (size_t)n * 16;
    float p[2];
    #pragma unroll
    for (int ph = 0; ph < 2; ++ph) {
        float M = -1e30f;
        #pragma unroll
        for (int g = 0; g < 8; ++g) M = fmaxf(M, st[ph * 8 + g].x);
        float S = 0.f, E = 0.f;
        #pragma unroll
        for (int g = 0; g < 8; ++g) {
            const float4 q = st[ph * 8 + g];
            const float sc = __expf(q.x - M);
            S += q.y * sc;
            E += q.z * sc;
        }
        p[ph] = E / S;
    }
    out[n] = p[0] * p[1];
}

extern "C" void kernel_launch(void* const* d_in, const int* in_sizes, int n_in,
                              void* d_out, int out_size, void* d_ws, size_t ws_size,
                              hipStream_t stream) {
    const float* x      = (const float*)d_in[0];
    const int*   target = (const int*)  d_in[1];
    const float* W1     = (const float*)d_in[2];
    const float* b1     = (const float*)d_in[3];
    const float* W2     = (const float*)d_in[4];
    const float* b2     = (const float*)d_in[5];
    float* out = (float*)d_out;
    int*   wsi = (int*)d_ws;

    const int ntok = in_sizes[1];   // 4096
    const int maxgrid = 2 * (NC + ntok / TB) + 2 * (ntok / TB);     // 962
    const int pregrid = 1 + (ntok * D) / (256 * 8) + 64 + 1;        // 1090

    k_prep_pre<<<pregrid, 256, 0, stream>>>(x, W1, b1, target, wsi, ntok);
    k_main    <<<maxgrid, 512, 0, stream>>>(target, W2, b2, wsi);
    k_combine <<<(ntok + 255) / 256, 256, 0, stream>>>(wsi, out, ntok);
}

// Round 14
// 54.954 us; speedup vs baseline: 4.0062x; 4.0062x over previous
//
#include <hip/hip_runtime.h>
#include <cmath>

typedef _Float16 half8 __attribute__((ext_vector_type(8)));
typedef float f32x4 __attribute__((ext_vector_type(4)));

constexpr int D   = 512;
constexpr int NC  = 225;   // classes
constexpr int NPC = 224;   // outputs per class
constexpr int N1  = 256;   // padded W1 cols
constexpr int TB  = 32;    // tokens per chunk

// ws layout (int units)
constexpr int WS_NCHUNK = 0;
constexpr int WS_CHUNK  = 16;        // 962*4 ints (cls,start,cnt,colhalf)
constexpr int WS_ORDER  = 4096;      // 4096 ids grouped by class
constexpr int WS_B1P    = 8192;      // 256 floats padded b1
constexpr int WS_W1H    = 8448;      // 256*512 halves, [col][k]
constexpr int WS_W1L    = 73984;
constexpr int WS_XH     = 139520;    // 4096*512 halves
constexpr int WS_XL     = 1188096;
constexpr int WS_STAT   = 2236672;   // 4096 * 16 * float4 {m,s,e,0}; ph1 g0-7, ph2 g8-15

// fp16 split: hi = RTN(v), flushed to 0 if subnormal; lo = RTN((v-hi)*2048)
__device__ __forceinline__ void f16split(float v, _Float16& h, _Float16& l) {
    _Float16 hh = (_Float16)v;
    float hf = (float)hh;
    if (fabsf(hf) < 6.104e-5f) { hh = (_Float16)0.f; hf = 0.f; }
    h = hh;
    l = (_Float16)((v - hf) * 2048.0f);
}

// ---------- merged prep (block 0) + convert pre-pass (blocks 1..) ----------
__global__ __launch_bounds__(256) void k_prep_pre(
    const float* __restrict__ x, const float* __restrict__ W1,
    const float* __restrict__ b1, const int* __restrict__ target,
    int* __restrict__ ws, int ntok)
{
    const int bid = blockIdx.x, tid = threadIdx.x;
    if (bid == 0) {
        __shared__ int h[256], sc[256], sc2[256], cur[NC];
        h[tid] = 0;
        __syncthreads();
        for (int n = tid; n < ntok; n += 256) atomicAdd(&h[target[n] / NPC], 1);
        __syncthreads();
        const int hv = h[tid];
        sc[tid] = hv; __syncthreads();
        for (int o = 1; o < 256; o <<= 1) {
            int a = (tid >= o) ? sc[tid - o] : 0;
            __syncthreads();
            sc[tid] += a;
            __syncthreads();
        }
        const int start = sc[tid] - hv;
        const int nch = (tid < NC) ? (hv + TB - 1) / TB : 0;
        sc2[tid] = nch; __syncthreads();
        for (int o = 1; o < 256; o <<= 1) {
            int a = (tid >= o) ? sc2[tid - o] : 0;
            __syncthreads();
            sc2[tid] += a;
            __syncthreads();
        }
        const int nch2 = sc2[255];
        if (tid < NC) {
            cur[tid] = start;
            const int cb = sc2[tid] - nch;
            for (int j = 0; j < nch; ++j) {
                for (int q = 0; q < 2; ++q) {
                    const int e = WS_CHUNK + (((cb + j) * 2) + q) * 4;
                    ws[e + 0] = tid;
                    ws[e + 1] = start + j * TB;
                    ws[e + 2] = min(TB, hv - j * TB);
                    ws[e + 3] = q;
                }
            }
        }
        const int P1C = ntok / TB;      // 128
        if (tid < P1C) {
            for (int q = 0; q < 2; ++q) {
                const int e = WS_CHUNK + (nch2 * 2 + tid * 2 + q) * 4;
                ws[e + 0] = -1;
                ws[e + 1] = tid * TB;
                ws[e + 2] = TB;
                ws[e + 3] = q;
            }
        }
        if (tid == 0) ws[WS_NCHUNK] = nch2 * 2 + P1C * 2;
        __syncthreads();
        for (int n = tid; n < ntok; n += 256) {
            const int c = target[n] / NPC;
            const int pos = atomicAdd(&cur[c], 1);
            ws[WS_ORDER + pos] = n;
        }
        return;
    }
    const int pb = bid - 1;
    _Float16* xh  = (_Float16*)(ws + WS_XH);
    _Float16* xl  = (_Float16*)(ws + WS_XL);
    _Float16* w1h = (_Float16*)(ws + WS_W1H);
    _Float16* w1l = (_Float16*)(ws + WS_W1L);
    const int XBLK = (ntok * D) / (256 * 8);           // 1024
    if (pb < XBLK) {
        const int base = (pb * 256 + tid) * 8;
        const float4 a = *(const float4*)(x + base);
        const float4 b = *(const float4*)(x + base + 4);
        const float v[8] = {a.x, a.y, a.z, a.w, b.x, b.y, b.z, b.w};
        half8 hv, lv;
        #pragma unroll
        for (int j = 0; j < 8; ++j) {
            _Float16 hq, lq;
            f16split(v[j], hq, lq);
            hv[j] = hq; lv[j] = lq;
        }
        *(half8*)(xh + base) = hv;
        *(half8*)(xl + base) = lv;
    } else if (pb < XBLK + 64) {
        const int oi = ((pb - XBLK) * 256 + tid) * 8;  // [c][k], 8 k each
        const int c = oi >> 9, k0 = oi & 511;
        half8 hv, lv;
        #pragma unroll
        for (int j = 0; j < 8; ++j) {
            const float v = (c < NC) ? W1[(size_t)(k0 + j) * NC + c] : 0.f;
            _Float16 hq, lq;
            f16split(v, hq, lq);
            hv[j] = hq; lv[j] = lq;
        }
        *(half8*)(w1h + oi) = hv;
        *(half8*)(w1l + oi) = lv;
    } else {
        float* b1p = (float*)ws + WS_B1P;
        if (tid < N1) b1p[tid] = (tid < NC) ? b1[tid] : 0.f;
    }
}

// load B fragments from pre-converted x
#define LX(bh, bl, kk)                                                           \
    do {                                                                         \
        _Pragma("unroll")                                                        \
        for (int n = 0; n < 2; ++n) if (n < ntiles) {                            \
            bh[n] = *(const half8*)(xh + xoff[n] + (kk) + l4 * 8);               \
            bl[n] = *(const half8*)(xl + xoff[n] + (kk) + l4 * 8);               \
        }                                                                        \
    } while (0)

// load A fragments from pre-converted W1
#define LA(ah, al, kk)                                                           \
    do {                                                                         \
        _Pragma("unroll")                                                        \
        for (int mi = 0; mi < 2; ++mi) if (tval[mi]) {                           \
            const int col_ = (mt0 + mi) * 16 + l15;                              \
            ah[mi] = *(const half8*)(w1h + (size_t)col_ * D + (kk) + l4 * 8);    \
            al[mi] = *(const half8*)(w1l + (size_t)col_ * D + (kk) + l4 * 8);    \
        }                                                                        \
    } while (0)

// 12 MFMA from preloaded A (phase 1)
#define PROCA(ah, al, bh, bl)                                                    \
    do {                                                                         \
        _Pragma("unroll")                                                        \
        for (int mi = 0; mi < 2; ++mi) if (tval[mi]) {                           \
            _Pragma("unroll")                                                    \
            for (int n = 0; n < 2; ++n) if (n < ntiles) {                        \
                accA[mi][n] = __builtin_amdgcn_mfma_f32_16x16x32_f16(ah[mi], bh[n], accA[mi][n], 0, 0, 0); \
                accB[mi][n] = __builtin_amdgcn_mfma_f32_16x16x32_f16(ah[mi], bl[n], accB[mi][n], 0, 0, 0); \
                accB[mi][n] = __builtin_amdgcn_mfma_f32_16x16x32_f16(al[mi], bh[n], accB[mi][n], 0, 0, 0); \
            }                                                                    \
        }                                                                        \
    } while (0)

// ---------- phase 2: LDS-staged W2 (global_load_lds dbuf) ----------
__device__ __forceinline__ void run_p2(
    const int* __restrict__ target, const float* __restrict__ W2c,
    const float* __restrict__ bsrc,
    const _Float16* __restrict__ xh, const _Float16* __restrict__ xl,
    int* __restrict__ ws, int* __restrict__ stok, float* __restrict__ wtile,
    int start, int cnt, int ch)
{
    const int tid = threadIdx.x, w = tid >> 6, lane = tid & 63;
    const int l15 = lane & 15, l4 = lane >> 4;

    if (tid < TB) stok[tid] = ws[WS_ORDER + start + min(tid, cnt - 1)];
    __syncthreads();

    const int ntiles = (cnt + 15) >> 4;
    int xoff[2];
    xoff[0] = stok[l15] * D;
    xoff[1] = stok[16 + l15] * D;

    const int lt0 = w * 2;                        // local col-tile base (0,2,4,6)
    bool tval[2];
    tval[0] = (lt0 < 7);
    tval[1] = (lt0 + 1 < 7);

    f32x4 accA[2][2] = {}, accB[2][2] = {};

    const char* gW = (const char*)W2c + ch * 448;     // this block's col-half

    // stage K-tile kt (32 rows x 112 cols f32 = 14336 B) into wtile[buf]
    #define STAGE(buf, kt)                                                          \
        do {                                                                        \
            const char* gb_ = gW + (size_t)(kt) * 28672;                            \
            _Pragma("unroll")                                                       \
            for (int i_ = 0; i_ < 4; ++i_) {                                        \
                const int ii_ = w + i_ * 4;                                         \
                if (ii_ < 14) {                                                     \
                    const int flat_ = ii_ * 1024 + lane * 16;                       \
                    const int row_ = flat_ / 448, off_ = flat_ % 448;               \
                    __builtin_amdgcn_global_load_lds(                               \
                        (const __attribute__((address_space(1))) uint32_t*)         \
                            (gb_ + (size_t)row_ * 896 + off_),                      \
                        (__attribute__((address_space(3))) uint32_t*)               \
                            (wtile + (buf) * 3584 + ii_ * 256),                     \
                        16, 0, 0);                                                  \
                }                                                                   \
            }                                                                       \
        } while (0)

    STAGE(0, 0);
    __syncthreads();

    for (int kt = 0; kt < 16; ++kt) {
        const int cur = kt & 1;
        if (kt + 1 < 16) STAGE(cur ^ 1, kt + 1);
        const int k0 = kt * 32;
        half8 Bh[2], Bl[2];
        LX(Bh, Bl, k0);
        #pragma unroll
        for (int mi = 0; mi < 2; ++mi) if (tval[mi]) {
            half8 Ah, Al;
            const float* wrow = wtile + cur * 3584 + (lt0 + mi) * 16 + l15;
            #pragma unroll
            for (int j = 0; j < 8; ++j) {
                _Float16 hq, lq;
                f16split(wrow[(l4 * 8 + j) * 112], hq, lq);
                Ah[j] = hq; Al[j] = lq;
            }
            #pragma unroll
            for (int n = 0; n < 2; ++n) if (n < ntiles) {
                accA[mi][n] = __builtin_amdgcn_mfma_f32_16x16x32_f16(Ah, Bh[n], accA[mi][n], 0, 0, 0);
                accB[mi][n] = __builtin_amdgcn_mfma_f32_16x16x32_f16(Ah, Bl[n], accB[mi][n], 0, 0, 0);
                accB[mi][n] = __builtin_amdgcn_mfma_f32_16x16x32_f16(Al, Bh[n], accB[mi][n], 0, 0, 0);
            }
        }
        __syncthreads();   // next-tile DMA done + wtile[cur] safe to reuse
    }
    #undef STAGE

    // ---- epilogue: per-wave per-token partial softmax stats ----
    float* stat = (float*)ws + WS_STAT;
    #pragma unroll
    for (int n = 0; n < 2; ++n) {
        if (n < ntiles) {
            const int tok = stok[n * 16 + l15];
            const int tcol = target[tok] % NPC;
            float vals[2][4];
            float mx = -1e30f;
            #pragma unroll
            for (int mi = 0; mi < 2; ++mi) if (tval[mi]) {
                const int col0 = (ch * 7 + lt0 + mi) * 16 + l4 * 4;
                const float4 bv = *(const float4*)(bsrc + col0);
                #pragma unroll
                for (int r = 0; r < 4; ++r) {
                    const float v = accA[mi][n][r] + accB[mi][n][r] * (1.f / 2048.f) + (&bv.x)[r];
                    vals[mi][r] = v;
                    mx = fmaxf(mx, v);
                }
            }
            mx = fmaxf(mx, __shfl_xor(mx, 16, 64));
            mx = fmaxf(mx, __shfl_xor(mx, 32, 64));
            float s = 0.f, e = 0.f;
            #pragma unroll
            for (int mi = 0; mi < 2; ++mi) if (tval[mi]) {
                const int col0 = (ch * 7 + lt0 + mi) * 16 + l4 * 4;
                #pragma unroll
                for (int r = 0; r < 4; ++r) {
                    const float ex = __expf(vals[mi][r] - mx);
                    s += ex;
                    if (col0 + r == tcol) e = ex;
                }
            }
            s += __shfl_xor(s, 16, 64); s += __shfl_xor(s, 32, 64);
            e += __shfl_xor(e, 16, 64); e += __shfl_xor(e, 32, 64);
            if (l4 == 0) {
                const int g = 8 + ch * 4 + w;
                *(float4*)(stat + (size_t)tok * 64 + g * 4) = {mx, s, e, 0.f};
            }
        }
    }
}

// ---------- phase 1: R12 path (pre-converted W1, register dbuf) ----------
__device__ __forceinline__ void run_p1(
    const int* __restrict__ target, const float* __restrict__ bsrc,
    const _Float16* __restrict__ w1h, const _Float16* __restrict__ w1l,
    const _Float16* __restrict__ xh, const _Float16* __restrict__ xl,
    int* __restrict__ ws, int* __restrict__ stok,
    int start, int cnt, int ch)
{
    constexpr int NREAL = NC;
    const int tid = threadIdx.x, w = tid >> 6, lane = tid & 63;
    const int l15 = lane & 15, l4 = lane >> 4;

    if (tid < TB) stok[tid] = start + tid;
    __syncthreads();

    const int ntiles = 2;
    int xoff[2];
    xoff[0] = stok[l15] * D;
    xoff[1] = stok[16 + l15] * D;

    const int mt0 = ch * 8 + w * 2;
    bool tval[2];
    tval[0] = (mt0 * 16) < NREAL;
    tval[1] = ((mt0 + 1) * 16) < NREAL;

    f32x4 accA[2][2] = {}, accB[2][2] = {};

    half8 aha[2], ala[2], ahb[2], alb[2];
    half8 xha[2], xla[2], xhb[2], xlb[2];
    LA(aha, ala, 0); LX(xha, xla, 0);
    for (int k0 = 0; k0 < D; k0 += 64) {
        LA(ahb, alb, k0 + 32); LX(xhb, xlb, k0 + 32);
        PROCA(aha, ala, xha, xla);
        if (k0 + 64 < D) { LA(aha, ala, k0 + 64); LX(xha, xla, k0 + 64); }
        PROCA(ahb, alb, xhb, xlb);
    }

    float* stat = (float*)ws + WS_STAT;
    #pragma unroll
    for (int n = 0; n < 2; ++n) {
        const int tok = stok[n * 16 + l15];
        const int tcol = target[tok] / NPC;
        float vals[2][4];
        float mx = -1e30f;
        #pragma unroll
        for (int mi = 0; mi < 2; ++mi) {
            const int col0 = (mt0 + mi) * 16 + l4 * 4;
            const float4 bv = *(const float4*)(bsrc + col0);
            #pragma unroll
            for (int r = 0; r < 4; ++r) {
                const float v = accA[mi][n][r] + accB[mi][n][r] * (1.f / 2048.f) + (&bv.x)[r];
                vals[mi][r] = v;
                if (col0 + r < NREAL) mx = fmaxf(mx, v);
            }
        }
        mx = fmaxf(mx, __shfl_xor(mx, 16, 64));
        mx = fmaxf(mx, __shfl_xor(mx, 32, 64));
        float s = 0.f, e = 0.f;
        #pragma unroll
        for (int mi = 0; mi < 2; ++mi) {
            const int col0 = (mt0 + mi) * 16 + l4 * 4;
            #pragma unroll
            for (int r = 0; r < 4; ++r) {
                const int cr = col0 + r;
                if (cr < NREAL) {
                    const float ex = __expf(vals[mi][r] - mx);
                    s += ex;
                    if (cr == tcol) e = ex;
                }
            }
        }
        s += __shfl_xor(s, 16, 64); s += __shfl_xor(s, 32, 64);
        e += __shfl_xor(e, 16, 64); e += __shfl_xor(e, 32, 64);
        if (l4 == 0) {
            const int g = ch * 4 + w;
            *(float4*)(stat + (size_t)tok * 64 + g * 4) = {mx, s, e, 0.f};
        }
    }
}

__global__ __launch_bounds__(256, 4) void k_main(
    const int* __restrict__ target, const float* __restrict__ W2,
    const float* __restrict__ b2, int* __restrict__ ws)
{
    __shared__ float wtile[2 * 3584];   // 28 KB W2 staging
    __shared__ int stok[TB];
    const int bid = blockIdx.x;
    if (bid >= ws[WS_NCHUNK]) return;
    const int4 ce = *(const int4*)(ws + WS_CHUNK + bid * 4);
    const _Float16* w1h = (const _Float16*)(ws + WS_W1H);
    const _Float16* w1l = (const _Float16*)(ws + WS_W1L);
    const _Float16* xh  = (const _Float16*)(ws + WS_XH);
    const _Float16* xl  = (const _Float16*)(ws + WS_XL);
    if (ce.x >= 0) {
        run_p2(target, W2 + (size_t)ce.x * D * NPC, b2 + ce.x * NPC,
               xh, xl, ws, stok, wtile, ce.y, ce.z, ce.w);
    } else {
        run_p1(target, (const float*)ws + WS_B1P, w1h, w1l,
               xh, xl, ws, stok, ce.y, ce.z, ce.w);
    }
}

// ---------- combine: merge 8 stat groups per phase, out = p1*p2 ----------
__global__ __launch_bounds__(256) void k_combine(const int* __restrict__ ws,
                                                 float* __restrict__ out, int ntok) {
    const int n = blockIdx.x * 256 + threadIdx.x;
    if (n >= ntok) return;
    const float4* st = (const float4*)((const float*)ws + WS_STAT) + (size_t)n * 16;
    float p[2];
    #pragma unroll
    for (int ph = 0; ph < 2; ++ph) {
        float M = -1e30f;
        #pragma unroll
        for (int g = 0; g < 8; ++g) M = fmaxf(M, st[ph * 8 + g].x);
        float S = 0.f, E = 0.f;
        #pragma unroll
        for (int g = 0; g < 8; ++g) {
            const float4 q = st[ph * 8 + g];
            const float sc = __expf(q.x - M);
            S += q.y * sc;
            E += q.z * sc;
        }
        p[ph] = E / S;
    }
    out[n] = p[0] * p[1];
}

extern "C" void kernel_launch(void* const* d_in, const int* in_sizes, int n_in,
                              void* d_out, int out_size, void* d_ws, size_t ws_size,
                              hipStream_t stream) {
    const float* x      = (const float*)d_in[0];
    const int*   target = (const int*)  d_in[1];
    const float* W1     = (const float*)d_in[2];
    const float* b1     = (const float*)d_in[3];
    const float* W2     = (const float*)d_in[4];
    const float* b2     = (const float*)d_in[5];
    float* out = (float*)d_out;
    int*   wsi = (int*)d_ws;

    const int ntok = in_sizes[1];   // 4096
    const int maxgrid = 2 * (NC + ntok / TB) + 2 * (ntok / TB);     // 962
    const int pregrid = 1 + (ntok * D) / (256 * 8) + 64 + 1;        // 1090

    k_prep_pre<<<pregrid, 256, 0, stream>>>(x, W1, b1, target, wsi, ntok);
    k_main    <<<maxgrid, 256, 0, stream>>>(target, W2, b2, wsi);
    k_combine <<<(ntok + 255) / 256, 256, 0, stream>>>(wsi, out, ntok);
}

// Round 15
// 47.926 us; speedup vs baseline: 4.5937x; 1.1466x over previous
//
#include <hip/hip_runtime.h>
#include <cmath>

typedef _Float16 half8 __attribute__((ext_vector_type(8)));
typedef float f32x4 __attribute__((ext_vector_type(4)));

constexpr int D   = 512;
constexpr int NC  = 225;   // classes
constexpr int NPC = 224;   // outputs per class
constexpr int N1  = 256;   // padded W1 cols
constexpr int TB  = 32;    // tokens per chunk

// ws layout (int units)
constexpr int WS_NCHUNK = 0;
constexpr int WS_CHUNK  = 16;        // 962*4 ints (cls,start,cnt,colhalf)
constexpr int WS_ORDER  = 4096;      // 4096 ids grouped by class
constexpr int WS_B1P    = 8192;      // 256 floats padded b1
constexpr int WS_W1H    = 8448;      // 256*512 halves, [col][k]
constexpr int WS_W1L    = 73984;
constexpr int WS_XH     = 139520;    // 4096*512 halves
constexpr int WS_XL     = 1188096;
constexpr int WS_STAT   = 2236672;   // 4096 * 16 * float4 {m,s,e,0}

// fp16 split: hi = RTN(v), flushed to 0 if subnormal; lo = RTN((v-hi)*2048)
__device__ __forceinline__ void f16split(float v, _Float16& h, _Float16& l) {
    _Float16 hh = (_Float16)v;
    float hf = (float)hh;
    if (fabsf(hf) < 6.104e-5f) { hh = (_Float16)0.f; hf = 0.f; }
    h = hh;
    l = (_Float16)((v - hf) * 2048.0f);
}

// ---------- merged prep (block 0) + convert pre-pass (blocks 1..) ----------
__global__ __launch_bounds__(256) void k_prep_pre(
    const float* __restrict__ x, const float* __restrict__ W1,
    const float* __restrict__ b1, const int* __restrict__ target,
    int* __restrict__ ws, int ntok)
{
    const int bid = blockIdx.x, tid = threadIdx.x;
    if (bid == 0) {
        __shared__ int h[256], sc[256], sc2[256], cur[NC];
        h[tid] = 0;
        __syncthreads();
        for (int n = tid; n < ntok; n += 256) atomicAdd(&h[target[n] / NPC], 1);
        __syncthreads();
        const int hv = h[tid];
        sc[tid] = hv; __syncthreads();
        for (int o = 1; o < 256; o <<= 1) {
            int a = (tid >= o) ? sc[tid - o] : 0;
            __syncthreads();
            sc[tid] += a;
            __syncthreads();
        }
        const int start = sc[tid] - hv;
        const int nch = (tid < NC) ? (hv + TB - 1) / TB : 0;
        sc2[tid] = nch; __syncthreads();
        for (int o = 1; o < 256; o <<= 1) {
            int a = (tid >= o) ? sc2[tid - o] : 0;
            __syncthreads();
            sc2[tid] += a;
            __syncthreads();
        }
        const int nch2 = sc2[255];
        if (tid < NC) {
            cur[tid] = start;
            const int cb = sc2[tid] - nch;
            for (int j = 0; j < nch; ++j) {
                for (int q = 0; q < 2; ++q) {
                    const int e = WS_CHUNK + (((cb + j) * 2) + q) * 4;
                    ws[e + 0] = tid;
                    ws[e + 1] = start + j * TB;
                    ws[e + 2] = min(TB, hv - j * TB);
                    ws[e + 3] = q;
                }
            }
        }
        const int P1C = ntok / TB;      // 128
        if (tid < P1C) {
            for (int q = 0; q < 2; ++q) {
                const int e = WS_CHUNK + (nch2 * 2 + tid * 2 + q) * 4;
                ws[e + 0] = -1;
                ws[e + 1] = tid * TB;
                ws[e + 2] = TB;
                ws[e + 3] = q;
            }
        }
        if (tid == 0) ws[WS_NCHUNK] = nch2 * 2 + P1C * 2;
        __syncthreads();
        for (int n = tid; n < ntok; n += 256) {
            const int c = target[n] / NPC;
            const int pos = atomicAdd(&cur[c], 1);
            ws[WS_ORDER + pos] = n;
        }
        return;
    }
    const int pb = bid - 1;
    _Float16* xh  = (_Float16*)(ws + WS_XH);
    _Float16* xl  = (_Float16*)(ws + WS_XL);
    _Float16* w1h = (_Float16*)(ws + WS_W1H);
    _Float16* w1l = (_Float16*)(ws + WS_W1L);
    const int XBLK = (ntok * D) / (256 * 8);           // 1024
    if (pb < XBLK) {
        const int base = (pb * 256 + tid) * 8;
        const float4 a = *(const float4*)(x + base);
        const float4 b = *(const float4*)(x + base + 4);
        const float v[8] = {a.x, a.y, a.z, a.w, b.x, b.y, b.z, b.w};
        half8 hv, lv;
        #pragma unroll
        for (int j = 0; j < 8; ++j) {
            _Float16 hq, lq;
            f16split(v[j], hq, lq);
            hv[j] = hq; lv[j] = lq;
        }
        *(half8*)(xh + base) = hv;
        *(half8*)(xl + base) = lv;
    } else if (pb < XBLK + 64) {
        const int oi = ((pb - XBLK) * 256 + tid) * 8;  // [c][k], 8 k each
        const int c = oi >> 9, k0 = oi & 511;
        half8 hv, lv;
        #pragma unroll
        for (int j = 0; j < 8; ++j) {
            const float v = (c < NC) ? W1[(size_t)(k0 + j) * NC + c] : 0.f;
            _Float16 hq, lq;
            f16split(v, hq, lq);
            hv[j] = hq; lv[j] = lq;
        }
        *(half8*)(w1h + oi) = hv;
        *(half8*)(w1l + oi) = lv;
    } else {
        float* b1p = (float*)ws + WS_B1P;
        if (tid < N1) b1p[tid] = (tid < NC) ? b1[tid] : 0.f;
    }
}

// ---------- main: DMA-staged W (p2) + DMA-staged x (both) ----------
template <bool PH2>
__device__ __forceinline__ void run_chunk(
    const int* __restrict__ target, const float* __restrict__ W2c,
    const float* __restrict__ bsrc,
    const _Float16* __restrict__ w1h, const _Float16* __restrict__ w1l,
    const _Float16* __restrict__ xh_g, const _Float16* __restrict__ xl_g,
    int* __restrict__ ws, int* __restrict__ stok,
    float* __restrict__ wtile, _Float16* __restrict__ xtile,
    int start, int cnt, int ch)
{
    constexpr int NREAL = PH2 ? NPC : NC;
    const int tid = threadIdx.x, w = tid >> 6, lane = tid & 63;
    const int l15 = lane & 15, l4 = lane >> 4;

    if (tid < TB)
        stok[tid] = PH2 ? ws[WS_ORDER + start + min(tid, cnt - 1)] : (start + tid);
    __syncthreads();

    const int ntiles = PH2 ? ((cnt + 15) >> 4) : 2;
    const int mt0 = PH2 ? (w * 2) : (ch * 8 + w * 2);   // p2: local col-tile
    bool tval[2];
    if (PH2) { tval[0] = (mt0 < 7); tval[1] = (mt0 + 1 < 7); }
    else     { tval[0] = (mt0 * 16) < NREAL; tval[1] = ((mt0 + 1) * 16) < NREAL; }

    // x-DMA lane source: wave part = h/l, halfsel = token half
    const int part = w >> 1, halfsel = w & 1;
    const int xtok = stok[halfsel * 16 + (lane >> 2)];
    const size_t xsrcoff = (size_t)xtok * 1024 + (size_t)(lane & 3) * 16;
    const char* xsrc = part ? (const char*)xl_g : (const char*)xh_g;
    const char* gW = PH2 ? ((const char*)W2c + ch * 448) : nullptr;

    #define STAGE_X(buf, kt)                                                        \
        __builtin_amdgcn_global_load_lds(                                           \
            (const __attribute__((address_space(1))) uint32_t*)                     \
                (xsrc + xsrcoff + (size_t)(kt) * 64),                               \
            (__attribute__((address_space(3))) uint32_t*)                           \
                ((char*)xtile + (buf) * 4096 + part * 2048 + halfsel * 1024),       \
            16, 0, 0)

    #define STAGE_W(buf, kt)                                                        \
        do {                                                                        \
            const char* gb_ = gW + (size_t)(kt) * 28672;                            \
            _Pragma("unroll")                                                       \
            for (int i_ = 0; i_ < 4; ++i_) {                                        \
                const int ii_ = w + i_ * 4;                                         \
                if (ii_ < 14) {                                                     \
                    const int flat_ = ii_ * 1024 + lane * 16;                       \
                    const int row_ = flat_ / 448, off_ = flat_ % 448;               \
                    __builtin_amdgcn_global_load_lds(                               \
                        (const __attribute__((address_space(1))) uint32_t*)         \
                            (gb_ + (size_t)row_ * 896 + off_),                      \
                        (__attribute__((address_space(3))) uint32_t*)               \
                            (wtile + (buf) * 3584 + ii_ * 256),                     \
                        16, 0, 0);                                                  \
                }                                                                   \
            }                                                                       \
        } while (0)

    f32x4 accA[2][2] = {}, accB[2][2] = {};

    if (PH2) STAGE_W(0, 0);
    STAGE_X(0, 0);
    __syncthreads();

    for (int kt = 0; kt < 16; ++kt) {
        const int cur = kt & 1;
        if (kt + 1 < 16) {
            if (PH2) STAGE_W(cur ^ 1, kt + 1);
            STAGE_X(cur ^ 1, kt + 1);
        }
        // B fragments from LDS
        const char* xb = (const char*)xtile + cur * 4096;
        half8 Bh[2], Bl[2];
        #pragma unroll
        for (int n = 0; n < 2; ++n) if (n < ntiles) {
            Bh[n] = *(const half8*)(xb + (n * 16 + l15) * 64 + l4 * 16);
            Bl[n] = *(const half8*)(xb + 2048 + (n * 16 + l15) * 64 + l4 * 16);
        }
        #pragma unroll
        for (int mi = 0; mi < 2; ++mi) if (tval[mi]) {
            half8 Ah, Al;
            if (PH2) {
                const float* wrow = wtile + cur * 3584 + (mt0 + mi) * 16 + l15;
                #pragma unroll
                for (int j = 0; j < 8; ++j) {
                    _Float16 hq, lq;
                    f16split(wrow[(l4 * 8 + j) * 112], hq, lq);
                    Ah[j] = hq; Al[j] = lq;
                }
            } else {
                const int col = (mt0 + mi) * 16 + l15;
                const int k0 = kt * 32;
                Ah = *(const half8*)(w1h + (size_t)col * D + k0 + l4 * 8);
                Al = *(const half8*)(w1l + (size_t)col * D + k0 + l4 * 8);
            }
            #pragma unroll
            for (int n = 0; n < 2; ++n) if (n < ntiles) {
                accA[mi][n] = __builtin_amdgcn_mfma_f32_16x16x32_f16(Ah, Bh[n], accA[mi][n], 0, 0, 0);
                accB[mi][n] = __builtin_amdgcn_mfma_f32_16x16x32_f16(Ah, Bl[n], accB[mi][n], 0, 0, 0);
                accB[mi][n] = __builtin_amdgcn_mfma_f32_16x16x32_f16(Al, Bh[n], accB[mi][n], 0, 0, 0);
            }
        }
        __syncthreads();
    }
    #undef STAGE_W
    #undef STAGE_X

    // ---- epilogue: per-wave per-token partial softmax stats {m, s, e_target} ----
    float* stat = (float*)ws + WS_STAT;
    #pragma unroll
    for (int n = 0; n < 2; ++n) {
        if (n < ntiles) {
            const int tok = stok[n * 16 + l15];
            const int tt  = target[tok];
            const int tcol = PH2 ? (tt % NPC) : (tt / NPC);
            float vals[2][4];
            float mx = -1e30f;
            #pragma unroll
            for (int mi = 0; mi < 2; ++mi) if (tval[mi]) {
                const int col0 = PH2 ? ((ch * 7 + mt0 + mi) * 16 + l4 * 4)
                                     : ((mt0 + mi) * 16 + l4 * 4);
                const float4 bv = *(const float4*)(bsrc + col0);
                #pragma unroll
                for (int r = 0; r < 4; ++r) {
                    const float v = accA[mi][n][r] + accB[mi][n][r] * (1.f / 2048.f) + (&bv.x)[r];
                    vals[mi][r] = v;
                    if (col0 + r < NREAL) mx = fmaxf(mx, v);
                }
            }
            mx = fmaxf(mx, __shfl_xor(mx, 16, 64));
            mx = fmaxf(mx, __shfl_xor(mx, 32, 64));
            float s = 0.f, e = 0.f;
            #pragma unroll
            for (int mi = 0; mi < 2; ++mi) if (tval[mi]) {
                const int col0 = PH2 ? ((ch * 7 + mt0 + mi) * 16 + l4 * 4)
                                     : ((mt0 + mi) * 16 + l4 * 4);
                #pragma unroll
                for (int r = 0; r < 4; ++r) {
                    const int cr = col0 + r;
                    if (cr < NREAL) {
                        const float ex = __expf(vals[mi][r] - mx);
                        s += ex;
                        if (cr == tcol) e = ex;
                    }
                }
            }
            s += __shfl_xor(s, 16, 64); s += __shfl_xor(s, 32, 64);
            e += __shfl_xor(e, 16, 64); e += __shfl_xor(e, 32, 64);
            if (l4 == 0) {
                const int g = (PH2 ? 8 : 0) + ch * 4 + w;
                *(float4*)(stat + (size_t)tok * 64 + g * 4) = {mx, s, e, 0.f};
            }
        }
    }
}

__global__ __launch_bounds__(256, 4) void k_main(
    const int* __restrict__ target, const float* __restrict__ W2,
    const float* __restrict__ b2, int* __restrict__ ws)
{
    __shared__ float wtile[2 * 3584];      // 28 KB
    __shared__ _Float16 xtile[2 * 2048];   // 8 KB
    __shared__ int stok[TB];
    const int bid = blockIdx.x;
    if (bid >= ws[WS_NCHUNK]) return;
    const int4 ce = *(const int4*)(ws + WS_CHUNK + bid * 4);
    const _Float16* w1h = (const _Float16*)(ws + WS_W1H);
    const _Float16* w1l = (const _Float16*)(ws + WS_W1L);
    const _Float16* xh  = (const _Float16*)(ws + WS_XH);
    const _Float16* xl  = (const _Float16*)(ws + WS_XL);
    if (ce.x >= 0) {
        run_chunk<true>(target, W2 + (size_t)ce.x * D * NPC, b2 + ce.x * NPC,
                        w1h, w1l, xh, xl, ws, stok, wtile, xtile, ce.y, ce.z, ce.w);
    } else {
        run_chunk<false>(target, nullptr, (const float*)ws + WS_B1P,
                         w1h, w1l, xh, xl, ws, stok, wtile, xtile, ce.y, ce.z, ce.w);
    }
}

// ---------- combine: merge 8 stat groups per phase, out = p1*p2 ----------
__global__ __launch_bounds__(256) void k_combine(const int* __restrict__ ws,
                                                 float* __restrict__ out, int ntok) {
    const int n = blockIdx.x * 256 + threadIdx.x;
    if (n >= ntok) return;
    const float4* st = (const float4*)((const float*)ws + WS_STAT) + (size_t)n * 16;
    float p[2];
    #pragma unroll
    for (int ph = 0; ph < 2; ++ph) {
        float M = -1e30f;
        #pragma unroll
        for (int g = 0; g < 8; ++g) M = fmaxf(M, st[ph * 8 + g].x);
        float S = 0.f, E = 0.f;
        #pragma unroll
        for (int g = 0; g < 8; ++g) {
            const float4 q = st[ph * 8 + g];
            const float sc = __expf(q.x - M);
            S += q.y * sc;
            E += q.z * sc;
        }
        p[ph] = E / S;
    }
    out[n] = p[0] * p[1];
}

extern "C" void kernel_launch(void* const* d_in, const int* in_sizes, int n_in,
                              void* d_out, int out_size, void* d_ws, size_t ws_size,
                              hipStream_t stream) {
    const float* x      = (const float*)d_in[0];
    const int*   target = (const int*)  d_in[1];
    const float* W1     = (const float*)d_in[2];
    const float* b1     = (const float*)d_in[3];
    const float* W2     = (const float*)d_in[4];
    const float* b2     = (const float*)d_in[5];
    float* out = (float*)d_out;
    int*   wsi = (int*)d_ws;

    const int ntok = in_sizes[1];   // 4096
    const int maxgrid = 2 * (NC + ntok / TB) + 2 * (ntok / TB);     // 962
    const int pregrid = 1 + (ntok * D) / (256 * 8) + 64 + 1;        // 1090

    k_prep_pre<<<pregrid, 256, 0, stream>>>(x, W1, b1, target, wsi, ntok);
    k_main    <<<maxgrid, 256, 0, stream>>>(target, W2, b2, wsi);
    k_combine <<<(ntok + 255) / 256, 256, 0, stream>>>(wsi, out, ntok);
}